// Round 9
// baseline (181.371 us; speedup 1.0000x reference)
//
#include <hip/hip_runtime.h>

// UFO linear attention, MI355X (gfx950). B=8, N=4096, C=512, H=8, DK=DV=64.
//
// R12: R11's full-N core with the MFMA switched 16x16x32 -> 32x32x16
// (measured 15% faster pipe: 2382 vs 2075 TF ubench; half the MFMA
// instruction count per K-tile). Same LDS traffic, same staging/swizzle/
// sync (proven R11), same acc budget (64 regs). Epilogue reworked for the
// 32x32 C/D layout: col=lane&31, row=(reg&3)+8*(reg>>2)+4*(lane>>5);
// qnorm reduces within 32-lane halves (shfl_xor 1..16 stays in-half).

typedef __attribute__((ext_vector_type(4))) float f32x4;
typedef __attribute__((ext_vector_type(16))) float f32x16;
typedef __attribute__((ext_vector_type(8))) short s16x8;
typedef __attribute__((ext_vector_type(4))) unsigned short u16x4;
typedef __attribute__((ext_vector_type(2))) unsigned u32x2;

#define DEVFN __device__ __forceinline__

DEVFN unsigned short f2b(float f) {  // fp32 -> bf16 RNE
  union { float f; unsigned u; } un; un.f = f;
  unsigned r = un.u + 0x7fffu + ((un.u >> 16) & 1u);
  return (unsigned short)(r >> 16);
}
DEVFN float b2f(unsigned short us) {
  union { unsigned u; float f; } un; un.u = ((unsigned)us) << 16;
  return un.f;
}
// pack two fp32 -> dword of 2 bf16 (round-half-up): 2 adds + 1 v_perm
DEVFN unsigned pk2(float x0, float x1) {
  union { float f; unsigned u; } a, b;
  a.f = x0; b.f = x1;
  return __builtin_amdgcn_perm(b.u + 0x8000u, a.u + 0x8000u, 0x07060302u);
}
// async global->LDS, 16 B per lane; lds dest = wave-uniform base + lane*16
DEVFN void gl_lds16(const void* g, void* l) {
  __builtin_amdgcn_global_load_lds(
      (const __attribute__((address_space(1))) unsigned*)g,
      (__attribute__((address_space(3))) unsigned*)l, 16, 0, 0);
}

// ---------------------------------------------------------------------------
// M-tile 128 x FULL N=512, BK=32, K=512 (16 K-tiles). 1024 thr = 16 waves,
// wave-tile 64x64 as 2x2 of 32x32 MFMA frags (mw = wid>>3, nw = wid&7).
// C[m][n] = sum_k A[m][k]*Bt[n][k] + bias[n]; optional fused head-norm
// (wave's 64 cols == one head == nw).
// ---------------------------------------------------------------------------
template <bool AF32, typename CT>
DEVFN void gemmN512(const void* Ain, const unsigned short* Bt,
                    const float* bias, CT* C, bool qnorm,
                    const float* gamma, int bx) {
  __shared__ __align__(16) char LA[2][8192];   // [buf][128 rows][64 B]
  __shared__ __align__(16) char LB[2][32768];  // [buf][512 rows][64 B]
  const int tid = threadIdx.x, lane = tid & 63, wid = tid >> 6;  // 0..15
  const int r5 = lane & 31, h = lane >> 5;
  const int mw = wid >> 3;  // 0..1  (M half)
  const int nw = wid & 7;   // 0..7  (N eighth = head)

  // B stage: 2 chunks/wave; chunk covers 16 rows; lane l -> row +(l>>2),
  // content-slot (l&3) taken from pre-swizzled source slot (l&3)^((l>>3)&3).
  const char* BsS = (const char*)Bt + (long)(wid * 32 + (lane >> 2)) * 1024 +
                    (((lane & 3) ^ ((lane >> 3) & 3)) * 16);

  // A sources
  const char* AfS = nullptr;  // fp32 (proj): thread t -> row t>>3, piece t&7
  const char* AsS = nullptr;  // bf16 (final): waves 0..7 stage 1 chunk each
  int awr = 0;                // swizzled 8-B ds_write offset (proj)
  if constexpr (AF32) {
    AfS = (const char*)Ain + (long)(bx * 128 + (tid >> 3)) * 2048 +
          (tid & 7) * 16;
    const int row = tid >> 3, p = tid & 7;
    awr = row * 64 + (((p >> 1) ^ ((row >> 1) & 3)) << 4) + (p & 1) * 8;
  } else {
    AsS = (const char*)Ain + (long)(bx * 128 + wid * 16 + (lane >> 2)) * 1024 +
          (((lane & 3) ^ ((lane >> 3) & 3)) * 16);
  }

  f32x16 acc[2][2] = {};
  f32x4 pa;  // proj fp32 A staging (1 per thread)

#define SGB(BUF, KT)                                                           \
  gl_lds16(BsS + (KT)*64, LB[BUF] + wid * 2048);                               \
  gl_lds16(BsS + 16384 + (KT)*64, LB[BUF] + wid * 2048 + 1024);
#define SGA(BUF, KT)                                                           \
  if (wid < 8) { gl_lds16(AsS + (KT)*64, LA[BUF] + wid * 1024); }
#define LDA(KT) pa = *reinterpret_cast<const f32x4*>(AfS + (KT)*128);
#define WRA(BUF)                                                               \
  {                                                                            \
    u32x2 w;                                                                   \
    w[0] = pk2(pa[0], pa[1]);                                                  \
    w[1] = pk2(pa[2], pa[3]);                                                  \
    *reinterpret_cast<u32x2*>(LA[BUF] + awr) = w;                              \
  }
// 32x32x16 frags: row/col = lane&31; k-slot = ks*2 + (lane>>5); same
// 4-slot XOR swizzle as the (unchanged) write side.
#define COMPUTE(BUF)                                                           \
  {                                                                            \
    s16x8 a[2][2], b[2][2];                                                    \
    _Pragma("unroll") for (int ks = 0; ks < 2; ++ks)                           \
        _Pragma("unroll") for (int i = 0; i < 2; ++i) {                        \
      int ar = mw * 64 + i * 32 + r5;                                          \
      a[ks][i] = *reinterpret_cast<const s16x8*>(                              \
          LA[BUF] + ar * 64 + (((ks * 2 + h) ^ ((ar >> 1) & 3)) << 4));        \
      int br = nw * 64 + i * 32 + r5;                                          \
      b[ks][i] = *reinterpret_cast<const s16x8*>(                              \
          LB[BUF] + br * 64 + (((ks * 2 + h) ^ ((br >> 1) & 3)) << 4));        \
    }                                                                          \
    _Pragma("unroll") for (int ks = 0; ks < 2; ++ks)                           \
        _Pragma("unroll") for (int i = 0; i < 2; ++i)                          \
        _Pragma("unroll") for (int j = 0; j < 2; ++j) acc[i][j] =              \
        __builtin_amdgcn_mfma_f32_32x32x16_bf16(a[ks][i], b[ks][j],            \
                                                acc[i][j], 0, 0, 0);           \
  }

  // prologue: tile 0 -> buf 0
  if constexpr (AF32) {
    LDA(0) WRA(0)
  } else {
    SGA(0, 0)
  }
  SGB(0, 0)
  __syncthreads();

#pragma unroll 1
  for (int t = 0; t < 15; ++t) {
    const int cur = t & 1, nxt = cur ^ 1;
    if constexpr (AF32) { LDA(t + 1) }  // loads fly under COMPUTE
    SGB(nxt, t + 1)
    if constexpr (!AF32) { SGA(nxt, t + 1) }
    COMPUTE(cur)
    if constexpr (AF32) { WRA(nxt) }  // reg-dep wait lands after compute
    __syncthreads();
  }
  COMPUTE(1)

#undef SGB
#undef SGA
#undef LDA
#undef WRA
#undef COMPUTE

  // ---- epilogue (32x32 C/D: col=lane&31, row=(reg&3)+8*(reg>>2)+4*h) ----
  const int crow0 = bx * 128 + mw * 64;
  const int ccol0 = nw * 64 + r5;
#pragma unroll
  for (int j = 0; j < 2; ++j) {
    float bv = bias[ccol0 + j * 32];
#pragma unroll
    for (int i = 0; i < 2; ++i)
#pragma unroll
      for (int reg = 0; reg < 16; ++reg) acc[i][j][reg] += bv;
  }
  if (qnorm) {  // wave's 64 cols == head nw; L2-norm over them per row
    const float gam = gamma[nw];
#pragma unroll
    for (int i = 0; i < 2; ++i)
#pragma unroll
      for (int reg = 0; reg < 16; ++reg) {
        float s = acc[i][0][reg] * acc[i][0][reg] +
                  acc[i][1][reg] * acc[i][1][reg];
        s += __shfl_xor(s, 1);
        s += __shfl_xor(s, 2);
        s += __shfl_xor(s, 4);
        s += __shfl_xor(s, 8);
        s += __shfl_xor(s, 16);  // stays within 32-lane half (bit5 fixed)
        float sc = gam / sqrtf(s);
        acc[i][0][reg] *= sc;
        acc[i][1][reg] *= sc;
      }
  }
#pragma unroll
  for (int i = 0; i < 2; ++i)
#pragma unroll
    for (int j = 0; j < 2; ++j)
#pragma unroll
      for (int reg = 0; reg < 16; ++reg) {
        long row = crow0 + i * 32 + (reg & 3) + 8 * (reg >> 2) + 4 * h;
        int col = ccol0 + j * 32;
        if constexpr (sizeof(CT) == 2)
          C[row * 512 + col] = f2b(acc[i][j][reg]);
        else
          C[row * 512 + col] = acc[i][j][reg];
      }
}

__global__ __launch_bounds__(1024)
void proj_qkv(const float* __restrict__ Aq, const float* __restrict__ Ak,
              const float* __restrict__ Av, const unsigned short* __restrict__ Bq,
              const unsigned short* __restrict__ Bk, const unsigned short* __restrict__ Bv,
              const float* __restrict__ bq, const float* __restrict__ bk,
              const float* __restrict__ bv, unsigned short* __restrict__ Cq,
              unsigned short* __restrict__ Ck, unsigned short* __restrict__ Cv,
              const float* __restrict__ gamma) {
  const int z = blockIdx.y;
  const float* A = z == 0 ? Aq : (z == 1 ? Ak : Av);
  const unsigned short* B = z == 0 ? Bq : (z == 1 ? Bk : Bv);
  const float* bias = z == 0 ? bq : (z == 1 ? bk : bv);
  unsigned short* C = z == 0 ? Cq : (z == 1 ? Ck : Cv);
  gemmN512<true, unsigned short>(A, B, bias, C, z == 0, gamma, blockIdx.x);
}

__global__ __launch_bounds__(1024)
void gemm_final(const unsigned short* __restrict__ q, const unsigned short* __restrict__ Mt,
                const float* __restrict__ bo, float* __restrict__ out) {
  const int zb = blockIdx.y;
  gemmN512<false, float>(q + (long)zb * 2097152, Mt + (long)zb * 262144, bo,
                         out + (long)zb * 2097152, false, nullptr, blockIdx.x);
}

// ---------------------------------------------------------------------------
// kv partials: part[chunk][bh][dk][dv] = sum over 256 n of k outer v
// ---------------------------------------------------------------------------
#define NCHUNK 16
__global__ __launch_bounds__(256, 2)
void kv_partial(const unsigned short* __restrict__ kq,
                const unsigned short* __restrict__ vq,
                float* __restrict__ part) {
  const int tid = threadIdx.x;
  const int chunk = blockIdx.x;
  const int bh = blockIdx.y;
  const int b = bh >> 3, h = bh & 7;
  __shared__ float ks[32][64];
  __shared__ float vs[32][64];
  const int dk0 = (tid & 15) * 4;
  const int dv0 = (tid >> 4) * 4;
  float acc[4][4] = {};
  const long nbase = (long)b * 4096 + chunk * 256;

  for (int sub = 0; sub < 8; ++sub) {
    long n0 = nbase + sub * 32;
#pragma unroll
    for (int i = 0; i < 2; ++i) {
      int e = i * 256 + tid;
      int row = e >> 4, c4 = e & 15;
      long gofs = (n0 + row) * 512 + h * 64 + c4 * 4;
      u16x4 kk = *reinterpret_cast<const u16x4*>(kq + gofs);
      u16x4 vv = *reinterpret_cast<const u16x4*>(vq + gofs);
      f32x4 kf = {b2f(kk[0]), b2f(kk[1]), b2f(kk[2]), b2f(kk[3])};
      f32x4 vf = {b2f(vv[0]), b2f(vv[1]), b2f(vv[2]), b2f(vv[3])};
      *reinterpret_cast<f32x4*>(&ks[row][c4 * 4]) = kf;
      *reinterpret_cast<f32x4*>(&vs[row][c4 * 4]) = vf;
    }
    __syncthreads();
#pragma unroll 4
    for (int n = 0; n < 32; ++n) {
      f32x4 kk = *reinterpret_cast<const f32x4*>(&ks[n][dk0]);
      f32x4 vv = *reinterpret_cast<const f32x4*>(&vs[n][dv0]);
#pragma unroll
      for (int a = 0; a < 4; ++a)
#pragma unroll
        for (int c = 0; c < 4; ++c)
          acc[a][c] += kk[a] * vv[c];
    }
    __syncthreads();
  }
  float* pg = part + ((long)chunk * 64 + bh) * 4096;
#pragma unroll
  for (int a = 0; a < 4; ++a) {
    f32x4 o = {acc[a][0], acc[a][1], acc[a][2], acc[a][3]};
    *reinterpret_cast<f32x4*>(pg + (dk0 + a) * 64 + dv0) = o;
  }
}

// reduce partials + L2-norm rows (over dv) * gamma -> kvn bf16 [bh][64][64]
__global__ __launch_bounds__(256)
void kv_normN(const float* __restrict__ part, const float* __restrict__ gamma,
              unsigned short* __restrict__ kvn) {
  const int bh = blockIdx.x, h = bh & 7;
  const int tid = threadIdx.x;
  __shared__ float kvs[4096];
  __shared__ float scale[64];
#pragma unroll
  for (int i = 0; i < 4; ++i) {
    int e4 = i * 256 + tid;
    const float* p = part + (long)bh * 4096 + e4 * 4;
    f32x4 s = {0.f, 0.f, 0.f, 0.f};
#pragma unroll
    for (int c = 0; c < NCHUNK; ++c) {
      f32x4 v = *reinterpret_cast<const f32x4*>(p + (long)c * 64 * 4096);
      s += v;
    }
    *reinterpret_cast<f32x4*>(kvs + e4 * 4) = s;
  }
  __syncthreads();
  if (tid < 64) {
    float s = 0.f;
    for (int dv = 0; dv < 64; ++dv) { float x = kvs[tid * 64 + dv]; s += x * x; }
    scale[tid] = gamma[h] / sqrtf(s);
  }
  __syncthreads();
#pragma unroll
  for (int i = 0; i < 4; ++i) {
    int e4 = i * 256 + tid;
    float sc = scale[e4 >> 4];
    f32x4 v = *reinterpret_cast<const f32x4*>(kvs + e4 * 4);
    u16x4 o = {f2b(v[0] * sc), f2b(v[1] * sc), f2b(v[2] * sc), f2b(v[3] * sc)};
    *reinterpret_cast<u16x4*>(kvn + (long)bh * 4096 + e4 * 4) = o;
  }
}

// Mt[b][c][h*64+dk] = sum_dv Wo[c][h*64+dv] * kvn[b,h][dk][dv]
__global__ __launch_bounds__(64)
void mt_kernel(const unsigned short* __restrict__ Wo_b,
               const unsigned short* __restrict__ kvn,
               unsigned short* __restrict__ Mt) {
  const int bid = blockIdx.x;
  const int bh = bid >> 2, seg = bid & 3;
  const int b = bh >> 3, h = bh & 7;
  const int lane = threadIdx.x;
  const int r = lane & 15, g = lane >> 4;
  f32x4 acc[8][4] = {};
  s16x8 bf[2][4];
#pragma unroll
  for (int ks = 0; ks < 2; ++ks)
#pragma unroll
    for (int j = 0; j < 4; ++j)
      bf[ks][j] = *reinterpret_cast<const s16x8*>(
          kvn + (long)bh * 4096 + (j * 16 + r) * 64 + ks * 32 + g * 8);
#pragma unroll
  for (int ks = 0; ks < 2; ++ks)
#pragma unroll
    for (int i = 0; i < 8; ++i) {
      s16x8 af = *reinterpret_cast<const s16x8*>(
          Wo_b + (long)(seg * 128 + i * 16 + r) * 512 + h * 64 + ks * 32 + g * 8);
#pragma unroll
      for (int j = 0; j < 4; ++j)
        acc[i][j] = __builtin_amdgcn_mfma_f32_16x16x32_bf16(af, bf[ks][j], acc[i][j], 0, 0, 0);
    }
#pragma unroll
  for (int i = 0; i < 8; ++i)
#pragma unroll
    for (int j = 0; j < 4; ++j)
#pragma unroll
      for (int ii = 0; ii < 4; ++ii) {
        int c = seg * 128 + i * 16 + g * 4 + ii;
        int dk = j * 16 + r;
        Mt[(long)b * 262144 + (long)c * 512 + h * 64 + dk] = f2b(acc[i][j][ii]);
      }
}

__global__ void cast4(const float* __restrict__ a0, const float* __restrict__ a1,
                      const float* __restrict__ a2, const float* __restrict__ a3,
                      unsigned short* __restrict__ o0, unsigned short* __restrict__ o1,
                      unsigned short* __restrict__ o2, unsigned short* __restrict__ o3) {
  const int y = blockIdx.y;
  const float* in = y == 0 ? a0 : (y == 1 ? a1 : (y == 2 ? a2 : a3));
  unsigned short* out = y == 0 ? o0 : (y == 1 ? o1 : (y == 2 ? o2 : o3));
  int i = blockIdx.x * 256 + threadIdx.x;
  f32x4 v = reinterpret_cast<const f32x4*>(in)[i];
  reinterpret_cast<u16x4*>(out)[i] = u16x4{f2b(v[0]), f2b(v[1]), f2b(v[2]), f2b(v[3])};
}

// ---------------------------------------------------------------------------
extern "C" void kernel_launch(void* const* d_in, const int* in_sizes, int n_in,
                              void* d_out, int out_size, void* d_ws, size_t ws_size,
                              hipStream_t stream) {
  const float* queries = (const float*)d_in[0];
  const float* keys    = (const float*)d_in[1];
  const float* values  = (const float*)d_in[2];
  const float* Wq = (const float*)d_in[3];
  const float* bq = (const float*)d_in[4];
  const float* Wk = (const float*)d_in[5];
  const float* bk = (const float*)d_in[6];
  const float* Wv = (const float*)d_in[7];
  const float* bv = (const float*)d_in[8];
  const float* Wo = (const float*)d_in[9];
  const float* bo = (const float*)d_in[10];
  const float* gamma = (const float*)d_in[11];

  unsigned short* Wq_b = (unsigned short*)d_ws;            // 512 KB each
  unsigned short* Wk_b = Wq_b + 262144;
  unsigned short* Wv_b = Wk_b + 262144;
  unsigned short* Wo_b = Wv_b + 262144;
  unsigned short* q_b  = Wo_b + 262144;                    // 32 MB (holds q_n)
  unsigned short* kvn  = q_b + 16777216;                   // 512 KB
  float* part = (float*)(kvn + 262144);                    // 16 MB
  unsigned short* Mt = (unsigned short*)part;              // 4 MB (part dead by then)
  unsigned short* k_b = (unsigned short*)d_out;            // d_out scratch
  unsigned short* v_b = k_b + 16777216;
  float* out = (float*)d_out;

  cast4<<<dim3(256, 4), 256, 0, stream>>>(Wq, Wk, Wv, Wo, Wq_b, Wk_b, Wv_b, Wo_b);

  proj_qkv<<<dim3(256, 3), 1024, 0, stream>>>(
      queries, keys, values, Wq_b, Wk_b, Wv_b, bq, bk, bv, q_b, k_b, v_b, gamma);

  kv_partial<<<dim3(NCHUNK, 64), 256, 0, stream>>>(k_b, v_b, part);
  kv_normN<<<64, 256, 0, stream>>>(part, gamma, kvn);
  mt_kernel<<<256, 64, 0, stream>>>(Wo_b, kvn, Mt);

  gemm_final<<<dim3(32, 8), 1024, 0, stream>>>(q_b, Mt, bo, out);
}

// Round 10
// 176.452 us; speedup vs baseline: 1.0279x; 1.0279x over previous
//
#include <hip/hip_runtime.h>

// UFO linear attention, MI355X (gfx950). B=8, N=4096, C=512, H=8, DK=DV=64.
//
// R13: revert R12's 32x32 MFMA (regression: 4-way bank conflict, 6.29M)
// back to R11's proven 16x16x32 core (111.9 us, 0 conflicts). Spend the
// round on the tail: kv_partial vectorized to u16x8 (16 B/lane, G13) and
// NCHUNK 16->8 (halves fp32 partial write+read traffic, same FLOPs).

typedef __attribute__((ext_vector_type(4))) float f32x4;
typedef __attribute__((ext_vector_type(8))) short s16x8;
typedef __attribute__((ext_vector_type(4))) unsigned short u16x4;
typedef __attribute__((ext_vector_type(8))) unsigned short u16x8;
typedef __attribute__((ext_vector_type(2))) unsigned u32x2;

#define DEVFN __device__ __forceinline__

DEVFN unsigned short f2b(float f) {  // fp32 -> bf16 RNE
  union { float f; unsigned u; } un; un.f = f;
  unsigned r = un.u + 0x7fffu + ((un.u >> 16) & 1u);
  return (unsigned short)(r >> 16);
}
DEVFN float b2f(unsigned short us) {
  union { unsigned u; float f; } un; un.u = ((unsigned)us) << 16;
  return un.f;
}
// pack two fp32 -> dword of 2 bf16 (round-half-up): 2 adds + 1 v_perm
DEVFN unsigned pk2(float x0, float x1) {
  union { float f; unsigned u; } a, b;
  a.f = x0; b.f = x1;
  return __builtin_amdgcn_perm(b.u + 0x8000u, a.u + 0x8000u, 0x07060302u);
}
// async global->LDS, 16 B per lane; lds dest = wave-uniform base + lane*16
DEVFN void gl_lds16(const void* g, void* l) {
  __builtin_amdgcn_global_load_lds(
      (const __attribute__((address_space(1))) unsigned*)g,
      (__attribute__((address_space(3))) unsigned*)l, 16, 0, 0);
}

// ---------------------------------------------------------------------------
// M-tile 128 x FULL N=512, BK=32, K=512 (16 K-tiles). 1024 thr = 16 waves,
// wave-tile 64x64 (mw = wid>>3 in 0..1, nw = wid&7 in 0..7).
// C[m][n] = sum_k A[m][k]*Bt[n][k] + bias[n]; optional fused head-norm
// (wave's 64 cols == one head == nw).  [R11 core, verbatim]
// ---------------------------------------------------------------------------
template <bool AF32, typename CT>
DEVFN void gemmN512(const void* Ain, const unsigned short* Bt,
                    const float* bias, CT* C, bool qnorm,
                    const float* gamma, int bx) {
  __shared__ __align__(16) char LA[2][8192];   // [buf][128 rows][64 B]
  __shared__ __align__(16) char LB[2][32768];  // [buf][512 rows][64 B]
  const int tid = threadIdx.x, lane = tid & 63, wid = tid >> 6;  // 0..15
  const int r = lane & 15, g = lane >> 4;
  const int mw = wid >> 3;  // 0..1  (M half)
  const int nw = wid & 7;   // 0..7  (N eighth = head)

  // B stage: 2 chunks/wave; chunk covers 16 rows; lane l -> row +(l>>2),
  // content-slot (l&3) taken from pre-swizzled source slot (l&3)^((l>>3)&3).
  const char* BsS = (const char*)Bt + (long)(wid * 32 + (lane >> 2)) * 1024 +
                    (((lane & 3) ^ ((lane >> 3) & 3)) * 16);

  // A sources
  const char* AfS = nullptr;  // fp32 (proj): thread t -> row t>>3, piece t&7
  const char* AsS = nullptr;  // bf16 (final): waves 0..7 stage 1 chunk each
  int awr = 0;                // swizzled 8-B ds_write offset (proj)
  if constexpr (AF32) {
    AfS = (const char*)Ain + (long)(bx * 128 + (tid >> 3)) * 2048 +
          (tid & 7) * 16;
    const int row = tid >> 3, p = tid & 7;
    awr = row * 64 + (((p >> 1) ^ ((row >> 1) & 3)) << 4) + (p & 1) * 8;
  } else {
    AsS = (const char*)Ain + (long)(bx * 128 + wid * 16 + (lane >> 2)) * 1024 +
          (((lane & 3) ^ ((lane >> 3) & 3)) * 16);
  }

  f32x4 acc[4][4] = {};
  f32x4 pa;  // proj fp32 A staging (1 per thread)

#define SGB(BUF, KT)                                                           \
  gl_lds16(BsS + (KT)*64, LB[BUF] + wid * 2048);                               \
  gl_lds16(BsS + 16384 + (KT)*64, LB[BUF] + wid * 2048 + 1024);
#define SGA(BUF, KT)                                                           \
  if (wid < 8) { gl_lds16(AsS + (KT)*64, LA[BUF] + wid * 1024); }
#define LDA(KT) pa = *reinterpret_cast<const f32x4*>(AfS + (KT)*128);
#define WRA(BUF)                                                               \
  {                                                                            \
    u32x2 w;                                                                   \
    w[0] = pk2(pa[0], pa[1]);                                                  \
    w[1] = pk2(pa[2], pa[3]);                                                  \
    *reinterpret_cast<u32x2*>(LA[BUF] + awr) = w;                              \
  }
#define COMPUTE(BUF)                                                           \
  {                                                                            \
    s16x8 a[4], b[4];                                                          \
    _Pragma("unroll") for (int i = 0; i < 4; ++i) {                            \
      int ar = mw * 64 + i * 16 + r;                                           \
      a[i] = *reinterpret_cast<const s16x8*>(                                  \
          LA[BUF] + ar * 64 + ((g ^ ((ar >> 1) & 3)) << 4));                   \
    }                                                                          \
    _Pragma("unroll") for (int j = 0; j < 4; ++j) {                            \
      int br = nw * 64 + j * 16 + r;                                           \
      b[j] = *reinterpret_cast<const s16x8*>(                                  \
          LB[BUF] + br * 64 + ((g ^ ((br >> 1) & 3)) << 4));                   \
    }                                                                          \
    _Pragma("unroll") for (int i = 0; i < 4; ++i)                              \
        _Pragma("unroll") for (int j = 0; j < 4; ++j) acc[i][j] =              \
        __builtin_amdgcn_mfma_f32_16x16x32_bf16(a[i], b[j], acc[i][j], 0, 0,   \
                                                0);                            \
  }

  // prologue: tile 0 -> buf 0
  if constexpr (AF32) {
    LDA(0) WRA(0)
  } else {
    SGA(0, 0)
  }
  SGB(0, 0)
  __syncthreads();

#pragma unroll 1
  for (int t = 0; t < 15; ++t) {
    const int cur = t & 1, nxt = cur ^ 1;
    if constexpr (AF32) { LDA(t + 1) }  // loads fly under COMPUTE
    SGB(nxt, t + 1)
    if constexpr (!AF32) { SGA(nxt, t + 1) }
    COMPUTE(cur)
    if constexpr (AF32) { WRA(nxt) }  // reg-dep wait lands after compute
    __syncthreads();
  }
  COMPUTE(1)

#undef SGB
#undef SGA
#undef LDA
#undef WRA
#undef COMPUTE

  // ---- epilogue (C/D layout: col=lane&15, row=(lane>>4)*4+ii) ----
  const int crow0 = bx * 128 + mw * 64 + g * 4;
  const int ccol0 = nw * 64 + r;
#pragma unroll
  for (int j = 0; j < 4; ++j) {
    float bv = bias[ccol0 + j * 16];
#pragma unroll
    for (int i = 0; i < 4; ++i)
#pragma unroll
      for (int ii = 0; ii < 4; ++ii) acc[i][j][ii] += bv;
  }
  if (qnorm) {  // wave's 64 cols == head nw; L2-norm over them per row
    const float gam = gamma[nw];
#pragma unroll
    for (int i = 0; i < 4; ++i)
#pragma unroll
      for (int ii = 0; ii < 4; ++ii) {
        float s = 0.f;
#pragma unroll
        for (int j = 0; j < 4; ++j) s += acc[i][j][ii] * acc[i][j][ii];
        s += __shfl_xor(s, 1);
        s += __shfl_xor(s, 2);
        s += __shfl_xor(s, 4);
        s += __shfl_xor(s, 8);
        float sc = gam / sqrtf(s);
#pragma unroll
        for (int j = 0; j < 4; ++j) acc[i][j][ii] *= sc;
      }
  }
#pragma unroll
  for (int i = 0; i < 4; ++i)
#pragma unroll
    for (int j = 0; j < 4; ++j)
#pragma unroll
      for (int ii = 0; ii < 4; ++ii) {
        long row = crow0 + i * 16 + ii;
        int col = ccol0 + j * 16;
        if constexpr (sizeof(CT) == 2)
          C[row * 512 + col] = f2b(acc[i][j][ii]);
        else
          C[row * 512 + col] = acc[i][j][ii];
      }
}

__global__ __launch_bounds__(1024)
void proj_qkv(const float* __restrict__ Aq, const float* __restrict__ Ak,
              const float* __restrict__ Av, const unsigned short* __restrict__ Bq,
              const unsigned short* __restrict__ Bk, const unsigned short* __restrict__ Bv,
              const float* __restrict__ bq, const float* __restrict__ bk,
              const float* __restrict__ bv, unsigned short* __restrict__ Cq,
              unsigned short* __restrict__ Ck, unsigned short* __restrict__ Cv,
              const float* __restrict__ gamma) {
  const int z = blockIdx.y;
  const float* A = z == 0 ? Aq : (z == 1 ? Ak : Av);
  const unsigned short* B = z == 0 ? Bq : (z == 1 ? Bk : Bv);
  const float* bias = z == 0 ? bq : (z == 1 ? bk : bv);
  unsigned short* C = z == 0 ? Cq : (z == 1 ? Ck : Cv);
  gemmN512<true, unsigned short>(A, B, bias, C, z == 0, gamma, blockIdx.x);
}

__global__ __launch_bounds__(1024)
void gemm_final(const unsigned short* __restrict__ q, const unsigned short* __restrict__ Mt,
                const float* __restrict__ bo, float* __restrict__ out) {
  const int zb = blockIdx.y;
  gemmN512<false, float>(q + (long)zb * 2097152, Mt + (long)zb * 262144, bo,
                         out + (long)zb * 2097152, false, nullptr, blockIdx.x);
}

// ---------------------------------------------------------------------------
// kv partials: part[chunk][bh][dk][dv] = sum over 512 n of k outer v
// u16x8 loads (16 B/lane); NCHUNK=8 halves partial traffic vs 16.
// ---------------------------------------------------------------------------
#define NCHUNK 8
__global__ __launch_bounds__(256, 2)
void kv_partial(const unsigned short* __restrict__ kq,
                const unsigned short* __restrict__ vq,
                float* __restrict__ part) {
  const int tid = threadIdx.x;
  const int chunk = blockIdx.x;  // 0..7
  const int bh = blockIdx.y;     // 0..63
  const int b = bh >> 3, h = bh & 7;
  __shared__ float ks[32][64];
  __shared__ float vs[32][64];
  const int dk0 = (tid & 15) * 4;
  const int dv0 = (tid >> 4) * 4;
  float acc[4][4] = {};
  const long nbase = (long)b * 4096 + chunk * 512;
  const int lrow = tid >> 3, lc8 = tid & 7;  // 32 rows x 8 col-groups of 8

  for (int sub = 0; sub < 16; ++sub) {
    long n0 = nbase + sub * 32;
    {
      long gofs = (n0 + lrow) * 512 + h * 64 + lc8 * 8;
      u16x8 kk = *reinterpret_cast<const u16x8*>(kq + gofs);
      u16x8 vv = *reinterpret_cast<const u16x8*>(vq + gofs);
      f32x4 k0 = {b2f(kk[0]), b2f(kk[1]), b2f(kk[2]), b2f(kk[3])};
      f32x4 k1 = {b2f(kk[4]), b2f(kk[5]), b2f(kk[6]), b2f(kk[7])};
      f32x4 v0 = {b2f(vv[0]), b2f(vv[1]), b2f(vv[2]), b2f(vv[3])};
      f32x4 v1 = {b2f(vv[4]), b2f(vv[5]), b2f(vv[6]), b2f(vv[7])};
      *reinterpret_cast<f32x4*>(&ks[lrow][lc8 * 8]) = k0;
      *reinterpret_cast<f32x4*>(&ks[lrow][lc8 * 8 + 4]) = k1;
      *reinterpret_cast<f32x4*>(&vs[lrow][lc8 * 8]) = v0;
      *reinterpret_cast<f32x4*>(&vs[lrow][lc8 * 8 + 4]) = v1;
    }
    __syncthreads();
#pragma unroll 4
    for (int n = 0; n < 32; ++n) {
      f32x4 kk = *reinterpret_cast<const f32x4*>(&ks[n][dk0]);
      f32x4 vv = *reinterpret_cast<const f32x4*>(&vs[n][dv0]);
#pragma unroll
      for (int a = 0; a < 4; ++a)
#pragma unroll
        for (int c = 0; c < 4; ++c)
          acc[a][c] += kk[a] * vv[c];
    }
    __syncthreads();
  }
  float* pg = part + ((long)chunk * 64 + bh) * 4096;
#pragma unroll
  for (int a = 0; a < 4; ++a) {
    f32x4 o = {acc[a][0], acc[a][1], acc[a][2], acc[a][3]};
    *reinterpret_cast<f32x4*>(pg + (dk0 + a) * 64 + dv0) = o;
  }
}

// reduce partials + L2-norm rows (over dv) * gamma -> kvn bf16 [bh][64][64]
__global__ __launch_bounds__(256)
void kv_normN(const float* __restrict__ part, const float* __restrict__ gamma,
              unsigned short* __restrict__ kvn) {
  const int bh = blockIdx.x, h = bh & 7;
  const int tid = threadIdx.x;
  __shared__ float kvs[4096];
  __shared__ float scale[64];
#pragma unroll
  for (int i = 0; i < 4; ++i) {
    int e4 = i * 256 + tid;
    const float* p = part + (long)bh * 4096 + e4 * 4;
    f32x4 s = {0.f, 0.f, 0.f, 0.f};
#pragma unroll
    for (int c = 0; c < NCHUNK; ++c) {
      f32x4 v = *reinterpret_cast<const f32x4*>(p + (long)c * 64 * 4096);
      s += v;
    }
    *reinterpret_cast<f32x4*>(kvs + e4 * 4) = s;
  }
  __syncthreads();
  if (tid < 64) {
    float s = 0.f;
    for (int dv = 0; dv < 64; ++dv) { float x = kvs[tid * 64 + dv]; s += x * x; }
    scale[tid] = gamma[h] / sqrtf(s);
  }
  __syncthreads();
#pragma unroll
  for (int i = 0; i < 4; ++i) {
    int e4 = i * 256 + tid;
    float sc = scale[e4 >> 4];
    f32x4 v = *reinterpret_cast<const f32x4*>(kvs + e4 * 4);
    u16x4 o = {f2b(v[0] * sc), f2b(v[1] * sc), f2b(v[2] * sc), f2b(v[3] * sc)};
    *reinterpret_cast<u16x4*>(kvn + (long)bh * 4096 + e4 * 4) = o;
  }
}

// Mt[b][c][h*64+dk] = sum_dv Wo[c][h*64+dv] * kvn[b,h][dk][dv]
__global__ __launch_bounds__(64)
void mt_kernel(const unsigned short* __restrict__ Wo_b,
               const unsigned short* __restrict__ kvn,
               unsigned short* __restrict__ Mt) {
  const int bid = blockIdx.x;
  const int bh = bid >> 2, seg = bid & 3;
  const int b = bh >> 3, h = bh & 7;
  const int lane = threadIdx.x;
  const int r = lane & 15, g = lane >> 4;
  f32x4 acc[8][4] = {};
  s16x8 bf[2][4];
#pragma unroll
  for (int ks = 0; ks < 2; ++ks)
#pragma unroll
    for (int j = 0; j < 4; ++j)
      bf[ks][j] = *reinterpret_cast<const s16x8*>(
          kvn + (long)bh * 4096 + (j * 16 + r) * 64 + ks * 32 + g * 8);
#pragma unroll
  for (int ks = 0; ks < 2; ++ks)
#pragma unroll
    for (int i = 0; i < 8; ++i) {
      s16x8 af = *reinterpret_cast<const s16x8*>(
          Wo_b + (long)(seg * 128 + i * 16 + r) * 512 + h * 64 + ks * 32 + g * 8);
#pragma unroll
      for (int j = 0; j < 4; ++j)
        acc[i][j] = __builtin_amdgcn_mfma_f32_16x16x32_bf16(af, bf[ks][j], acc[i][j], 0, 0, 0);
    }
#pragma unroll
  for (int i = 0; i < 8; ++i)
#pragma unroll
    for (int j = 0; j < 4; ++j)
#pragma unroll
      for (int ii = 0; ii < 4; ++ii) {
        int c = seg * 128 + i * 16 + g * 4 + ii;
        int dk = j * 16 + r;
        Mt[(long)b * 262144 + (long)c * 512 + h * 64 + dk] = f2b(acc[i][j][ii]);
      }
}

__global__ void cast4(const float* __restrict__ a0, const float* __restrict__ a1,
                      const float* __restrict__ a2, const float* __restrict__ a3,
                      unsigned short* __restrict__ o0, unsigned short* __restrict__ o1,
                      unsigned short* __restrict__ o2, unsigned short* __restrict__ o3) {
  const int y = blockIdx.y;
  const float* in = y == 0 ? a0 : (y == 1 ? a1 : (y == 2 ? a2 : a3));
  unsigned short* out = y == 0 ? o0 : (y == 1 ? o1 : (y == 2 ? o2 : o3));
  int i = blockIdx.x * 256 + threadIdx.x;
  f32x4 v = reinterpret_cast<const f32x4*>(in)[i];
  reinterpret_cast<u16x4*>(out)[i] = u16x4{f2b(v[0]), f2b(v[1]), f2b(v[2]), f2b(v[3])};
}

// ---------------------------------------------------------------------------
extern "C" void kernel_launch(void* const* d_in, const int* in_sizes, int n_in,
                              void* d_out, int out_size, void* d_ws, size_t ws_size,
                              hipStream_t stream) {
  const float* queries = (const float*)d_in[0];
  const float* keys    = (const float*)d_in[1];
  const float* values  = (const float*)d_in[2];
  const float* Wq = (const float*)d_in[3];
  const float* bq = (const float*)d_in[4];
  const float* Wk = (const float*)d_in[5];
  const float* bk = (const float*)d_in[6];
  const float* Wv = (const float*)d_in[7];
  const float* bv = (const float*)d_in[8];
  const float* Wo = (const float*)d_in[9];
  const float* bo = (const float*)d_in[10];
  const float* gamma = (const float*)d_in[11];

  unsigned short* Wq_b = (unsigned short*)d_ws;            // 512 KB each
  unsigned short* Wk_b = Wq_b + 262144;
  unsigned short* Wv_b = Wk_b + 262144;
  unsigned short* Wo_b = Wv_b + 262144;
  unsigned short* q_b  = Wo_b + 262144;                    // 32 MB (holds q_n)
  unsigned short* kvn  = q_b + 16777216;                   // 512 KB
  float* part = (float*)(kvn + 262144);                    // 8 MB
  unsigned short* Mt = (unsigned short*)part;              // 4 MB (part dead by then)
  unsigned short* k_b = (unsigned short*)d_out;            // d_out scratch
  unsigned short* v_b = k_b + 16777216;
  float* out = (float*)d_out;

  cast4<<<dim3(256, 4), 256, 0, stream>>>(Wq, Wk, Wv, Wo, Wq_b, Wk_b, Wv_b, Wo_b);

  proj_qkv<<<dim3(256, 3), 1024, 0, stream>>>(
      queries, keys, values, Wq_b, Wk_b, Wv_b, bq, bk, bv, q_b, k_b, v_b, gamma);

  kv_partial<<<dim3(NCHUNK, 64), 256, 0, stream>>>(k_b, v_b, part);
  kv_normN<<<64, 256, 0, stream>>>(part, gamma, kvn);
  mt_kernel<<<256, 64, 0, stream>>>(Wo_b, kvn, Mt);

  gemm_final<<<dim3(32, 8), 1024, 0, stream>>>(q_b, Mt, bo, out);
}

// Round 11
// 173.546 us; speedup vs baseline: 1.0451x; 1.0167x over previous
//
#include <hip/hip_runtime.h>

// UFO linear attention, MI355X (gfx950). B=8, N=4096, C=512, H=8, DK=DV=64.
//
// R14: consolidation. proj/gemm_final = R11/R13 proven core, untouched
// (VGPR 56 <= 64 keeps 8 waves/SIMD; at the 32-wave/CU hardware cap).
// kv_normN + mt_kernel merged into one kernel (kv_norm_mt): norm result
// kept in padded LDS (72-short pitch -> 16B-aligned b128 reads, ~2-way
// banks), mt phase runs as 4 waves = 4 segs. Mt relocated to part+8MB
// (inside the old 16 MB part footprint; no alias race with phase A).
// Saves a launch gap + the kvn global round-trip.

typedef __attribute__((ext_vector_type(4))) float f32x4;
typedef __attribute__((ext_vector_type(8))) short s16x8;
typedef __attribute__((ext_vector_type(4))) unsigned short u16x4;
typedef __attribute__((ext_vector_type(8))) unsigned short u16x8;
typedef __attribute__((ext_vector_type(2))) unsigned u32x2;

#define DEVFN __device__ __forceinline__

DEVFN unsigned short f2b(float f) {  // fp32 -> bf16 RNE
  union { float f; unsigned u; } un; un.f = f;
  unsigned r = un.u + 0x7fffu + ((un.u >> 16) & 1u);
  return (unsigned short)(r >> 16);
}
DEVFN float b2f(unsigned short us) {
  union { unsigned u; float f; } un; un.u = ((unsigned)us) << 16;
  return un.f;
}
// pack two fp32 -> dword of 2 bf16 (round-half-up): 2 adds + 1 v_perm
DEVFN unsigned pk2(float x0, float x1) {
  union { float f; unsigned u; } a, b;
  a.f = x0; b.f = x1;
  return __builtin_amdgcn_perm(b.u + 0x8000u, a.u + 0x8000u, 0x07060302u);
}
// async global->LDS, 16 B per lane; lds dest = wave-uniform base + lane*16
DEVFN void gl_lds16(const void* g, void* l) {
  __builtin_amdgcn_global_load_lds(
      (const __attribute__((address_space(1))) unsigned*)g,
      (__attribute__((address_space(3))) unsigned*)l, 16, 0, 0);
}

// ---------------------------------------------------------------------------
// M-tile 128 x FULL N=512, BK=32, K=512 (16 K-tiles). 1024 thr = 16 waves,
// wave-tile 64x64 (mw = wid>>3 in 0..1, nw = wid&7 in 0..7).
// C[m][n] = sum_k A[m][k]*Bt[n][k] + bias[n]; optional fused head-norm
// (wave's 64 cols == one head == nw).  [R11 core, verbatim]
// ---------------------------------------------------------------------------
template <bool AF32, typename CT>
DEVFN void gemmN512(const void* Ain, const unsigned short* Bt,
                    const float* bias, CT* C, bool qnorm,
                    const float* gamma, int bx) {
  __shared__ __align__(16) char LA[2][8192];   // [buf][128 rows][64 B]
  __shared__ __align__(16) char LB[2][32768];  // [buf][512 rows][64 B]
  const int tid = threadIdx.x, lane = tid & 63, wid = tid >> 6;  // 0..15
  const int r = lane & 15, g = lane >> 4;
  const int mw = wid >> 3;  // 0..1  (M half)
  const int nw = wid & 7;   // 0..7  (N eighth = head)

  // B stage: 2 chunks/wave; chunk covers 16 rows; lane l -> row +(l>>2),
  // content-slot (l&3) taken from pre-swizzled source slot (l&3)^((l>>3)&3).
  const char* BsS = (const char*)Bt + (long)(wid * 32 + (lane >> 2)) * 1024 +
                    (((lane & 3) ^ ((lane >> 3) & 3)) * 16);

  // A sources
  const char* AfS = nullptr;  // fp32 (proj): thread t -> row t>>3, piece t&7
  const char* AsS = nullptr;  // bf16 (final): waves 0..7 stage 1 chunk each
  int awr = 0;                // swizzled 8-B ds_write offset (proj)
  if constexpr (AF32) {
    AfS = (const char*)Ain + (long)(bx * 128 + (tid >> 3)) * 2048 +
          (tid & 7) * 16;
    const int row = tid >> 3, p = tid & 7;
    awr = row * 64 + (((p >> 1) ^ ((row >> 1) & 3)) << 4) + (p & 1) * 8;
  } else {
    AsS = (const char*)Ain + (long)(bx * 128 + wid * 16 + (lane >> 2)) * 1024 +
          (((lane & 3) ^ ((lane >> 3) & 3)) * 16);
  }

  f32x4 acc[4][4] = {};
  f32x4 pa;  // proj fp32 A staging (1 per thread)

#define SGB(BUF, KT)                                                           \
  gl_lds16(BsS + (KT)*64, LB[BUF] + wid * 2048);                               \
  gl_lds16(BsS + 16384 + (KT)*64, LB[BUF] + wid * 2048 + 1024);
#define SGA(BUF, KT)                                                           \
  if (wid < 8) { gl_lds16(AsS + (KT)*64, LA[BUF] + wid * 1024); }
#define LDA(KT) pa = *reinterpret_cast<const f32x4*>(AfS + (KT)*128);
#define WRA(BUF)                                                               \
  {                                                                            \
    u32x2 w;                                                                   \
    w[0] = pk2(pa[0], pa[1]);                                                  \
    w[1] = pk2(pa[2], pa[3]);                                                  \
    *reinterpret_cast<u32x2*>(LA[BUF] + awr) = w;                              \
  }
#define COMPUTE(BUF)                                                           \
  {                                                                            \
    s16x8 a[4], b[4];                                                          \
    _Pragma("unroll") for (int i = 0; i < 4; ++i) {                            \
      int ar = mw * 64 + i * 16 + r;                                           \
      a[i] = *reinterpret_cast<const s16x8*>(                                  \
          LA[BUF] + ar * 64 + ((g ^ ((ar >> 1) & 3)) << 4));                   \
    }                                                                          \
    _Pragma("unroll") for (int j = 0; j < 4; ++j) {                            \
      int br = nw * 64 + j * 16 + r;                                           \
      b[j] = *reinterpret_cast<const s16x8*>(                                  \
          LB[BUF] + br * 64 + ((g ^ ((br >> 1) & 3)) << 4));                   \
    }                                                                          \
    _Pragma("unroll") for (int i = 0; i < 4; ++i)                              \
        _Pragma("unroll") for (int j = 0; j < 4; ++j) acc[i][j] =              \
        __builtin_amdgcn_mfma_f32_16x16x32_bf16(a[i], b[j], acc[i][j], 0, 0,   \
                                                0);                            \
  }

  // prologue: tile 0 -> buf 0
  if constexpr (AF32) {
    LDA(0) WRA(0)
  } else {
    SGA(0, 0)
  }
  SGB(0, 0)
  __syncthreads();

#pragma unroll 1
  for (int t = 0; t < 15; ++t) {
    const int cur = t & 1, nxt = cur ^ 1;
    if constexpr (AF32) { LDA(t + 1) }  // loads fly under COMPUTE
    SGB(nxt, t + 1)
    if constexpr (!AF32) { SGA(nxt, t + 1) }
    COMPUTE(cur)
    if constexpr (AF32) { WRA(nxt) }  // reg-dep wait lands after compute
    __syncthreads();
  }
  COMPUTE(1)

#undef SGB
#undef SGA
#undef LDA
#undef WRA
#undef COMPUTE

  // ---- epilogue (C/D layout: col=lane&15, row=(lane>>4)*4+ii) ----
  const int crow0 = bx * 128 + mw * 64 + g * 4;
  const int ccol0 = nw * 64 + r;
#pragma unroll
  for (int j = 0; j < 4; ++j) {
    float bv = bias[ccol0 + j * 16];
#pragma unroll
    for (int i = 0; i < 4; ++i)
#pragma unroll
      for (int ii = 0; ii < 4; ++ii) acc[i][j][ii] += bv;
  }
  if (qnorm) {  // wave's 64 cols == head nw; L2-norm over them per row
    const float gam = gamma[nw];
#pragma unroll
    for (int i = 0; i < 4; ++i)
#pragma unroll
      for (int ii = 0; ii < 4; ++ii) {
        float s = 0.f;
#pragma unroll
        for (int j = 0; j < 4; ++j) s += acc[i][j][ii] * acc[i][j][ii];
        s += __shfl_xor(s, 1);
        s += __shfl_xor(s, 2);
        s += __shfl_xor(s, 4);
        s += __shfl_xor(s, 8);
        float sc = gam / sqrtf(s);
#pragma unroll
        for (int j = 0; j < 4; ++j) acc[i][j][ii] *= sc;
      }
  }
#pragma unroll
  for (int i = 0; i < 4; ++i)
#pragma unroll
    for (int j = 0; j < 4; ++j)
#pragma unroll
      for (int ii = 0; ii < 4; ++ii) {
        long row = crow0 + i * 16 + ii;
        int col = ccol0 + j * 16;
        if constexpr (sizeof(CT) == 2)
          C[row * 512 + col] = f2b(acc[i][j][ii]);
        else
          C[row * 512 + col] = acc[i][j][ii];
      }
}

__global__ __launch_bounds__(1024)
void proj_qkv(const float* __restrict__ Aq, const float* __restrict__ Ak,
              const float* __restrict__ Av, const unsigned short* __restrict__ Bq,
              const unsigned short* __restrict__ Bk, const unsigned short* __restrict__ Bv,
              const float* __restrict__ bq, const float* __restrict__ bk,
              const float* __restrict__ bv, unsigned short* __restrict__ Cq,
              unsigned short* __restrict__ Ck, unsigned short* __restrict__ Cv,
              const float* __restrict__ gamma) {
  const int z = blockIdx.y;
  const float* A = z == 0 ? Aq : (z == 1 ? Ak : Av);
  const unsigned short* B = z == 0 ? Bq : (z == 1 ? Bk : Bv);
  const float* bias = z == 0 ? bq : (z == 1 ? bk : bv);
  unsigned short* C = z == 0 ? Cq : (z == 1 ? Ck : Cv);
  gemmN512<true, unsigned short>(A, B, bias, C, z == 0, gamma, blockIdx.x);
}

__global__ __launch_bounds__(1024)
void gemm_final(const unsigned short* __restrict__ q, const unsigned short* __restrict__ Mt,
                const float* __restrict__ bo, float* __restrict__ out) {
  const int zb = blockIdx.y;
  gemmN512<false, float>(q + (long)zb * 2097152, Mt + (long)zb * 262144, bo,
                         out + (long)zb * 2097152, false, nullptr, blockIdx.x);
}

// ---------------------------------------------------------------------------
// kv partials: part[chunk][bh][dk][dv] = sum over 512 n of k outer v
// u16x8 loads (16 B/lane); NCHUNK=8 (part = 8 MB; Mt lives at part+8MB).
// ---------------------------------------------------------------------------
#define NCHUNK 8
__global__ __launch_bounds__(256, 2)
void kv_partial(const unsigned short* __restrict__ kq,
                const unsigned short* __restrict__ vq,
                float* __restrict__ part) {
  const int tid = threadIdx.x;
  const int chunk = blockIdx.x;  // 0..7
  const int bh = blockIdx.y;     // 0..63
  const int b = bh >> 3, h = bh & 7;
  __shared__ float ks[32][64];
  __shared__ float vs[32][64];
  const int dk0 = (tid & 15) * 4;
  const int dv0 = (tid >> 4) * 4;
  float acc[4][4] = {};
  const long nbase = (long)b * 4096 + chunk * 512;
  const int lrow = tid >> 3, lc8 = tid & 7;  // 32 rows x 8 col-groups of 8

  for (int sub = 0; sub < 16; ++sub) {
    long n0 = nbase + sub * 32;
    {
      long gofs = (n0 + lrow) * 512 + h * 64 + lc8 * 8;
      u16x8 kk = *reinterpret_cast<const u16x8*>(kq + gofs);
      u16x8 vv = *reinterpret_cast<const u16x8*>(vq + gofs);
      f32x4 k0 = {b2f(kk[0]), b2f(kk[1]), b2f(kk[2]), b2f(kk[3])};
      f32x4 k1 = {b2f(kk[4]), b2f(kk[5]), b2f(kk[6]), b2f(kk[7])};
      f32x4 v0 = {b2f(vv[0]), b2f(vv[1]), b2f(vv[2]), b2f(vv[3])};
      f32x4 v1 = {b2f(vv[4]), b2f(vv[5]), b2f(vv[6]), b2f(vv[7])};
      *reinterpret_cast<f32x4*>(&ks[lrow][lc8 * 8]) = k0;
      *reinterpret_cast<f32x4*>(&ks[lrow][lc8 * 8 + 4]) = k1;
      *reinterpret_cast<f32x4*>(&vs[lrow][lc8 * 8]) = v0;
      *reinterpret_cast<f32x4*>(&vs[lrow][lc8 * 8 + 4]) = v1;
    }
    __syncthreads();
#pragma unroll 4
    for (int n = 0; n < 32; ++n) {
      f32x4 kk = *reinterpret_cast<const f32x4*>(&ks[n][dk0]);
      f32x4 vv = *reinterpret_cast<const f32x4*>(&vs[n][dv0]);
#pragma unroll
      for (int a = 0; a < 4; ++a)
#pragma unroll
        for (int c = 0; c < 4; ++c)
          acc[a][c] += kk[a] * vv[c];
    }
    __syncthreads();
  }
  float* pg = part + ((long)chunk * 64 + bh) * 4096;
#pragma unroll
  for (int a = 0; a < 4; ++a) {
    f32x4 o = {acc[a][0], acc[a][1], acc[a][2], acc[a][3]};
    *reinterpret_cast<f32x4*>(pg + (dk0 + a) * 64 + dv0) = o;
  }
}

// ---------------------------------------------------------------------------
// Merged: reduce partials + L2-norm (over dv) * gamma -> kvn in padded LDS,
// then Mt[b][c][h*64+dk] = sum_dv Wo[c][h*64+dv] * kvn[dk][dv] (4 waves = 4
// 128-col segs). kvn LDS pitch 72 shorts (144 B): 16-B-aligned b128 reads,
// banks spread (36 dwords/row -> 4r mod 32).
// ---------------------------------------------------------------------------
__global__ __launch_bounds__(256)
void kv_norm_mt(const float* __restrict__ part, const float* __restrict__ gamma,
                const unsigned short* __restrict__ Wo_b,
                unsigned short* __restrict__ Mt) {
  const int bh = blockIdx.x, h = bh & 7, b = bh >> 3;
  const int tid = threadIdx.x;
  __shared__ float kvs[4096];
  __shared__ float scale_s[64];
  __shared__ __align__(16) unsigned short kvn_l[64 * 72];  // padded

  // phase A: reduce 8 partial chunks
#pragma unroll
  for (int i = 0; i < 4; ++i) {
    int e4 = i * 256 + tid;
    const float* p = part + (long)bh * 4096 + e4 * 4;
    f32x4 s = {0.f, 0.f, 0.f, 0.f};
#pragma unroll
    for (int c = 0; c < NCHUNK; ++c) {
      f32x4 v = *reinterpret_cast<const f32x4*>(p + (long)c * 64 * 4096);
      s += v;
    }
    *reinterpret_cast<f32x4*>(kvs + e4 * 4) = s;
  }
  __syncthreads();
  if (tid < 64) {
    float s = 0.f;
    for (int dv = 0; dv < 64; ++dv) { float x = kvs[tid * 64 + dv]; s += x * x; }
    scale_s[tid] = gamma[h] / sqrtf(s);
  }
  __syncthreads();
#pragma unroll
  for (int i = 0; i < 4; ++i) {
    int e4 = i * 256 + tid;
    int row = e4 >> 4, c0 = (e4 & 15) * 4;
    float sc = scale_s[row];
    f32x4 v = *reinterpret_cast<const f32x4*>(kvs + e4 * 4);
    u16x4 o = {f2b(v[0] * sc), f2b(v[1] * sc), f2b(v[2] * sc), f2b(v[3] * sc)};
    *reinterpret_cast<u16x4*>(kvn_l + row * 72 + c0) = o;
  }
  __syncthreads();

  // phase B: mt for seg = wave id
  const int seg = tid >> 6;
  const int lane = tid & 63;
  const int r = lane & 15, g = lane >> 4;
  f32x4 acc[8][4] = {};
  s16x8 bf[2][4];
#pragma unroll
  for (int ks = 0; ks < 2; ++ks)
#pragma unroll
    for (int j = 0; j < 4; ++j)
      bf[ks][j] = *reinterpret_cast<const s16x8*>(
          kvn_l + (j * 16 + r) * 72 + ks * 32 + g * 8);
#pragma unroll
  for (int ks = 0; ks < 2; ++ks)
#pragma unroll
    for (int i = 0; i < 8; ++i) {
      s16x8 af = *reinterpret_cast<const s16x8*>(
          Wo_b + (long)(seg * 128 + i * 16 + r) * 512 + h * 64 + ks * 32 + g * 8);
#pragma unroll
      for (int j = 0; j < 4; ++j)
        acc[i][j] = __builtin_amdgcn_mfma_f32_16x16x32_bf16(af, bf[ks][j], acc[i][j], 0, 0, 0);
    }
#pragma unroll
  for (int i = 0; i < 8; ++i)
#pragma unroll
    for (int j = 0; j < 4; ++j)
#pragma unroll
      for (int ii = 0; ii < 4; ++ii) {
        int c = seg * 128 + i * 16 + g * 4 + ii;
        int dk = j * 16 + r;
        Mt[(long)b * 262144 + (long)c * 512 + h * 64 + dk] = f2b(acc[i][j][ii]);
      }
}

__global__ void cast4(const float* __restrict__ a0, const float* __restrict__ a1,
                      const float* __restrict__ a2, const float* __restrict__ a3,
                      unsigned short* __restrict__ o0, unsigned short* __restrict__ o1,
                      unsigned short* __restrict__ o2, unsigned short* __restrict__ o3) {
  const int y = blockIdx.y;
  const float* in = y == 0 ? a0 : (y == 1 ? a1 : (y == 2 ? a2 : a3));
  unsigned short* out = y == 0 ? o0 : (y == 1 ? o1 : (y == 2 ? o2 : o3));
  int i = blockIdx.x * 256 + threadIdx.x;
  f32x4 v = reinterpret_cast<const f32x4*>(in)[i];
  reinterpret_cast<u16x4*>(out)[i] = u16x4{f2b(v[0]), f2b(v[1]), f2b(v[2]), f2b(v[3])};
}

// ---------------------------------------------------------------------------
extern "C" void kernel_launch(void* const* d_in, const int* in_sizes, int n_in,
                              void* d_out, int out_size, void* d_ws, size_t ws_size,
                              hipStream_t stream) {
  const float* queries = (const float*)d_in[0];
  const float* keys    = (const float*)d_in[1];
  const float* values  = (const float*)d_in[2];
  const float* Wq = (const float*)d_in[3];
  const float* bq = (const float*)d_in[4];
  const float* Wk = (const float*)d_in[5];
  const float* bk = (const float*)d_in[6];
  const float* Wv = (const float*)d_in[7];
  const float* bv = (const float*)d_in[8];
  const float* Wo = (const float*)d_in[9];
  const float* bo = (const float*)d_in[10];
  const float* gamma = (const float*)d_in[11];

  unsigned short* Wq_b = (unsigned short*)d_ws;            // 512 KB each
  unsigned short* Wk_b = Wq_b + 262144;
  unsigned short* Wv_b = Wk_b + 262144;
  unsigned short* Wo_b = Wv_b + 262144;
  unsigned short* q_b  = Wo_b + 262144;                    // 32 MB (holds q_n)
  unsigned short* kvn  = q_b + 16777216;                   // 512 KB (unused)
  float* part = (float*)(kvn + 262144);                    // 8 MB
  unsigned short* Mt = (unsigned short*)(part + 2097152);  // 4 MB, after part
  unsigned short* k_b = (unsigned short*)d_out;            // d_out scratch
  unsigned short* v_b = k_b + 16777216;
  float* out = (float*)d_out;

  cast4<<<dim3(256, 4), 256, 0, stream>>>(Wq, Wk, Wv, Wo, Wq_b, Wk_b, Wv_b, Wo_b);

  proj_qkv<<<dim3(256, 3), 1024, 0, stream>>>(
      queries, keys, values, Wq_b, Wk_b, Wv_b, bq, bk, bv, q_b, k_b, v_b, gamma);

  kv_partial<<<dim3(NCHUNK, 64), 256, 0, stream>>>(k_b, v_b, part);
  kv_norm_mt<<<64, 256, 0, stream>>>(part, gamma, Wo_b, Mt);

  gemm_final<<<dim3(32, 8), 1024, 0, stream>>>(q_b, Mt, bo, out);
}